// Round 5
// baseline (702.788 us; speedup 1.0000x reference)
//
#include <hip/hip_runtime.h>
#include <math.h>

// Problem constants
#define B_    1024
#define D_    512
#define V_    100000
#define NT_   782             // n-tiles of 128 (782*128 = 100096)
#define EPS_  1e-7f
#define COSM  0.9210609940028851f   // cos(0.4)
#define SINM  0.3894183423086505f   // sin(0.4)

typedef __bf16 bf16x8 __attribute__((ext_vector_type(8)));
typedef float  f32x4  __attribute__((ext_vector_type(4)));

struct alignas(16) US8 { unsigned short h[8]; };

// round-to-nearest-even float -> bf16 bits (inputs finite)
__device__ __forceinline__ unsigned short f2bf(float f) {
  union { float f; unsigned u; } a; a.f = f;
  unsigned u = a.u;
  u += 0x7FFFu + ((u >> 16) & 1u);
  return (unsigned short)(u >> 16);
}

__device__ __forceinline__ void async_copy16(void* lds, const void* g) {
  __builtin_amdgcn_global_load_lds(
      (const __attribute__((address_space(1))) void*)g,
      (__attribute__((address_space(3))) void*)lds, 16, 0, 0);
}

// ---------------------------------------------------------------------------
// Kernel 1: L2-normalize rows of x -> bf16; zero S.
// grid 256 x block 256 (4 waves = 4 rows per block)
// ---------------------------------------------------------------------------
__global__ void x_prep(const float* __restrict__ x,
                       unsigned short* __restrict__ xb,
                       float* __restrict__ S) {
  int t = threadIdx.x;
  int lane = t & 63, wave = t >> 6;
  int row = blockIdx.x * 4 + wave;
  const float* xr = x + (size_t)row * D_;
  f32x4 a = *(const f32x4*)(xr + lane * 8);
  f32x4 b = *(const f32x4*)(xr + lane * 8 + 4);
  float ss = a[0]*a[0] + a[1]*a[1] + a[2]*a[2] + a[3]*a[3]
           + b[0]*b[0] + b[1]*b[1] + b[2]*b[2] + b[3]*b[3];
#pragma unroll
  for (int off = 32; off > 0; off >>= 1) ss += __shfl_xor(ss, off, 64);
  float inv = 1.0f / fmaxf(sqrtf(ss), 1e-12f);
  US8 pk;
#pragma unroll
  for (int j = 0; j < 4; ++j) pk.h[j]     = f2bf(a[j] * inv);
#pragma unroll
  for (int j = 0; j < 4; ++j) pk.h[4 + j] = f2bf(b[j] * inv);
  *(US8*)(xb + (size_t)row * D_ + lane * 8) = pk;
  if (lane == 0) S[row] = 0.0f;
}

// ---------------------------------------------------------------------------
// Kernel 2 (v5): BM=512 x BN=128 bf16 MFMA GEMM, 1024 threads / 16 waves
// (wave grid 8m x 2n, per-wave 64x64 = proven fragment/epilogue code).
// NO w_prep: B staged inline from fp32 w, converted exactly 2x total
// (BM=512 -> 2 m-tiles; pair shares an XCD so w re-read L2-hits).
// Thread <-> (col = t&127, kc = t>>7): 8 stride-V scalar loads (256B
// contiguous per wave-instr), one ds_write_b128 to [col][kc^(col&7)]
// (consecutive-col lane map -> 8 bank-groups x 4 lanes b128 = conflict-free,
// same structure as the measured-0-conflict read pattern; R0's 1.9e7
// conflicts came from its stride-4 col map). B regs for tile t+1 prefetch
// during MFMA(t) (register dbuf, no extra LDS). A via global_load_lds.
// Column ssq block-complete -> LDS reduce -> iwL. Fused ArcFace epilogue.
// LDS 86.5 KB, 1 block/CU (4 waves/SIMD). grid 1568 x block 1024.
// ---------------------------------------------------------------------------
#define BM 512
#define BN 128
#define BK 64
#define NKT (D_ / BK)

__global__ __launch_bounds__(1024) void gemm_fused(
    const unsigned short* __restrict__ xb,
    const float* __restrict__ w,
    const int* __restrict__ labels,
    float* __restrict__ S, float* __restrict__ Lb) {
  int bid = blockIdx.x;
  int xcd = bid & 7;
  int slot = bid >> 3;          // 0..195
  int tm = slot & 1;
  int tn = xcd * 98 + (slot >> 1);
  if (tn >= NT_) return;
  int m0 = tm * BM, n0 = tn * BN;

  // LDS slot p (16B chunks) holds (m = p>>3, kc = (p&7) ^ (m&7))
  __shared__ unsigned short Ab[BM * BK];  // 64 KB
  __shared__ unsigned short Bb[BN * BK];  // 16 KB
  __shared__ float sqred[8][BN];          // 4 KB
  __shared__ float iwL[BN];
  int t = threadIdx.x;
  int lane = t & 63;
  int q = lane >> 4, l15 = lane & 15;
  int wave = t >> 6;                      // 0..15
  int wm = (wave & 7) * 64, wn = (wave >> 3) * 64;
  f32x4 acc[4][4] = {};

  // ---- A staging addresses: pre-swizzled global src, linear LDS dest ----
  const unsigned short* gA[4]; unsigned short* lA[4];
#pragma unroll
  for (int j = 0; j < 4; ++j) {
    int p = t + 1024 * j;                 // 0..4095
    int m = p >> 3;
    int kc = (p & 7) ^ (m & 7);
    gA[j] = xb + (size_t)(m0 + m) * D_ + kc * 8;
    lA[j] = Ab + p * 8;
  }

  // ---- B staging: thread owns (col, kchunk) = one US8 chunk per K-step --
  int col = t & 127;
  int kc8 = t >> 7;                       // 0..7
  bool vok = (n0 + col) < V_;
  const float* wc = w + (size_t)(kc8 * 8) * V_ + n0 + col;
  unsigned short* bdst = &Bb[(col * 8 + (kc8 ^ (col & 7))) * 8];
  float ssq = 0.0f;

  // prologue: load B regs for tile 0
  float breg[8];
  if (vok) {
#pragma unroll
    for (int i = 0; i < 8; ++i) breg[i] = wc[(size_t)i * V_];
  } else {
#pragma unroll
    for (int i = 0; i < 8; ++i) breg[i] = 0.0f;
  }

  int h = l15 & 7;
  for (int tt = 0; tt < NKT; ++tt) {
    int kt = tt * BK;
    // issue A DMA first (latency ticks under the convert below)
#pragma unroll
    for (int j = 0; j < 4; ++j) async_copy16(lA[j], gA[j] + kt);

    // convert current B regs -> LDS (consumes breg)
    US8 pk;
#pragma unroll
    for (int i = 0; i < 8; ++i) {
      float v = breg[i];
      ssq += v * v;
      pk.h[i] = f2bf(v);
    }
    *(US8*)bdst = pk;
    __syncthreads();            // drains A-DMA + B ds_write visible

    // prefetch next tile's B into regs (overlaps MFMA below)
    if (tt + 1 < NKT) {
      const float* wn_ = wc + (size_t)(kt + BK) * V_;
      if (vok) {
#pragma unroll
        for (int i = 0; i < 8; ++i) breg[i] = wn_[(size_t)i * V_];
      }
    }

#pragma unroll
    for (int s = 0; s < 2; ++s) {
      int kx = s * 4 + q;
      bf16x8 af[4], bfr[4];
#pragma unroll
      for (int ri = 0; ri < 4; ++ri) {
        int row_ = wm + ri * 16 + l15;
        af[ri] = *(const bf16x8*)&Ab[(row_ * 8 + (kx ^ h)) * 8];
      }
#pragma unroll
      for (int ci = 0; ci < 4; ++ci) {
        int row_ = wn + ci * 16 + l15;
        bfr[ci] = *(const bf16x8*)&Bb[(row_ * 8 + (kx ^ h)) * 8];
      }
#pragma unroll
      for (int ri = 0; ri < 4; ++ri)
#pragma unroll
        for (int ci = 0; ci < 4; ++ci)
          acc[ri][ci] = __builtin_amdgcn_mfma_f32_16x16x32_bf16(
              af[ri], bfr[ci], acc[ri][ci], 0, 0, 0);
    }
    __syncthreads();            // Ab/Bb safe to overwrite next iter
  }

  // ---- column inv-norms: ssq is block-complete over K ----
  sqred[kc8][col] = ssq;
  __syncthreads();
  if (t < BN) {
    float tot = 0.0f;
#pragma unroll
    for (int p = 0; p < 8; ++p) tot += sqred[p][t];
    iwL[t] = ((n0 + t) < V_) ? 1.0f / fmaxf(sqrtf(tot), 1e-12f) : 0.0f;
  }
  __syncthreads();

  // ---- epilogue: C/D layout col = lane&15 (n side), row = q*4 + reg ----
  float iw[4]; int vcol[4];
#pragma unroll
  for (int ci = 0; ci < 4; ++ci) {
    int nl = wn + ci * 16 + l15;
    vcol[ci] = n0 + nl;
    iw[ci] = iwL[nl];
  }
#pragma unroll
  for (int ri = 0; ri < 4; ++ri) {
#pragma unroll
    for (int reg = 0; reg < 4; ++reg) {
      int ml = wm + ri * 16 + q * 4 + reg;
      int r = m0 + ml;
      int lab = labels[r];
      float s = 0.0f;
#pragma unroll
      for (int ci = 0; ci < 4; ++ci) {
        float cv = acc[ri][ci][reg] * iw[ci];
        cv = fminf(fmaxf(cv, -1.0f + EPS_), 1.0f - EPS_);
        float logit = cv;
        if (vcol[ci] == lab) {
          logit = cv * COSM - sqrtf(fmaxf(1.0f - cv * cv, 0.0f)) * SINM;
          Lb[r] = logit;               // unique writer across grid
        }
        s += (vcol[ci] < V_) ? __expf(logit) : 0.0f;
      }
      s += __shfl_xor(s, 1, 64);
      s += __shfl_xor(s, 2, 64);
      s += __shfl_xor(s, 4, 64);
      s += __shfl_xor(s, 8, 64);
      if (l15 == 0) atomicAdd(&S[r], s);
    }
  }
}

// ---------------------------------------------------------------------------
// Kernel 3: loss = mean(log(S) - label_logit)
// ---------------------------------------------------------------------------
__global__ void finalk(const float* __restrict__ S, const float* __restrict__ Lb,
                       float* __restrict__ out) {
  __shared__ float red[256];
  int t = threadIdx.x;
  float s = 0.0f;
  for (int i = t; i < B_; i += 256) s += logf(S[i]) - Lb[i];
  red[t] = s;
  __syncthreads();
  for (int o = 128; o > 0; o >>= 1) {
    if (t < o) red[t] += red[t + o];
    __syncthreads();
  }
  if (t == 0) out[0] = red[0] * (1.0f / B_);
}

// ---------------------------------------------------------------------------
extern "C" void kernel_launch(void* const* d_in, const int* in_sizes, int n_in,
                              void* d_out, int out_size, void* d_ws, size_t ws_size,
                              hipStream_t stream) {
  const float* x = (const float*)d_in[0];
  const float* w = (const float*)d_in[1];
  const int* labels = (const int*)d_in[2];
  float* out = (float*)d_out;
  char* ws = (char*)d_ws;
  // ws layout (16B-aligned):
  //   xb : 1024*512 bf16 = 1,048,576 B
  //   S  : 1024 f32, Lb : 1024 f32
  unsigned short* xb = (unsigned short*)ws;
  float* S  = (float*)(ws + 1048576ull);
  float* Lb = (float*)(ws + 1052672ull);

  x_prep<<<256, 256, 0, stream>>>(x, xb, S);
  gemm_fused<<<1568, 1024, 0, stream>>>(xb, w, labels, S, Lb);
  finalk<<<1, 256, 0, stream>>>(S, Lb, out);
}

// Round 6
// 459.666 us; speedup vs baseline: 1.5289x; 1.5289x over previous
//
#include <hip/hip_runtime.h>
#include <math.h>

// Problem constants
#define B_    1024
#define D_    512
#define V_    100000
#define NT_   782             // n-tiles of 128 (782*128 = 100096)
#define EPS_  1e-7f
#define COSM  0.9210609940028851f   // cos(0.4)
#define SINM  0.3894183423086505f   // sin(0.4)

typedef __bf16 bf16x8 __attribute__((ext_vector_type(8)));
typedef float  f32x4  __attribute__((ext_vector_type(4)));

struct alignas(16) US8 { unsigned short h[8]; };

// round-to-nearest-even float -> bf16 bits (inputs finite)
__device__ __forceinline__ unsigned short f2bf(float f) {
  union { float f; unsigned u; } a; a.f = f;
  unsigned u = a.u;
  u += 0x7FFFu + ((u >> 16) & 1u);
  return (unsigned short)(u >> 16);
}

__device__ __forceinline__ void async_copy16(void* lds, const void* g) {
  __builtin_amdgcn_global_load_lds(
      (const __attribute__((address_space(1))) void*)g,
      (__attribute__((address_space(3))) void*)lds, 16, 0, 0);
}

// ---------------------------------------------------------------------------
// Kernel 1: L2-normalize rows of x -> bf16; zero S.
// grid 256 x block 256 (4 waves = 4 rows per block)
// ---------------------------------------------------------------------------
__global__ void x_prep(const float* __restrict__ x,
                       unsigned short* __restrict__ xb,
                       float* __restrict__ S) {
  int t = threadIdx.x;
  int lane = t & 63, wave = t >> 6;
  int row = blockIdx.x * 4 + wave;
  const float* xr = x + (size_t)row * D_;
  f32x4 a = *(const f32x4*)(xr + lane * 8);
  f32x4 b = *(const f32x4*)(xr + lane * 8 + 4);
  float ss = a[0]*a[0] + a[1]*a[1] + a[2]*a[2] + a[3]*a[3]
           + b[0]*b[0] + b[1]*b[1] + b[2]*b[2] + b[3]*b[3];
#pragma unroll
  for (int off = 32; off > 0; off >>= 1) ss += __shfl_xor(ss, off, 64);
  float inv = 1.0f / fmaxf(sqrtf(ss), 1e-12f);
  US8 pk;
#pragma unroll
  for (int j = 0; j < 4; ++j) pk.h[j]     = f2bf(a[j] * inv);
#pragma unroll
  for (int j = 0; j < 4; ++j) pk.h[4 + j] = f2bf(b[j] * inv);
  *(US8*)(xb + (size_t)row * D_ + lane * 8) = pk;
  if (lane == 0) S[row] = 0.0f;
}

// ---------------------------------------------------------------------------
// Kernel 2 (v6): R3's proven geometry (BM=256 x BN=128, 512 thr / 8 waves,
// wave grid 4m x 2n, single-buffered, 2 blocks/CU) with INLINE B staging
// from fp32 w — no w_prep kernel, no wbT workspace.
//   A: global_load_lds from xb (proven path).
//   B: thread <-> (col = t&127, kcp = t>>7); per K-iter loads 2 chunks
//      (kcp, kcp+4) x 8 stride-V floats each (lanes = consecutive cols ->
//      256B contiguous per wave-instr), converts, 2x ds_write_b128 to
//      [col][chunk ^ (col&7)] — pattern measured conflict-free in R5
//      (SQ_LDS_BANK_CONFLICT = 0). NO register double-buffer of B (R5's
//      spill source); resident-block TLP hides the load latency (m114).
//   Column ssq block-complete over K -> LDS reduce -> iwL (R0-proven).
// __launch_bounds__(512,4): VGPR cap 128, R3-proven no-spill.
// w fp32 re-read 4x (tm-quad of each tn on same XCD -> L2 serves re-reads).
// Fused ArcFace epilogue. grid 3136 x block 512.
// ---------------------------------------------------------------------------
#define BM 256
#define BN 128
#define BK 64

__global__ __launch_bounds__(512, 4) void gemm_fused(
    const unsigned short* __restrict__ xb,
    const float* __restrict__ w,
    const int* __restrict__ labels,
    float* __restrict__ S, float* __restrict__ Lb) {
  int bid = blockIdx.x;
  int xcd = bid & 7;
  int slot = bid >> 3;          // 0..391
  int tm = slot & 3;
  int tn = xcd * 98 + (slot >> 2);
  if (tn >= NT_) return;
  int m0 = tm * BM, n0 = tn * BN;

  // LDS slot p (16B chunks) holds (m = p>>3, kc = (p&7) ^ (m&7))
  __shared__ unsigned short Ab[BM * BK];  // 32 KB
  __shared__ unsigned short Bb[BN * BK];  // 16 KB
  __shared__ float sqred[4][BN];          // 2 KB
  __shared__ float iwL[BN];               // 0.5 KB
  __shared__ int labT[BM];                // 1 KB
  int t = threadIdx.x;
  if (t < BM) labT[t] = labels[m0 + t];
  int lane = t & 63;
  int q = lane >> 4, l15 = lane & 15;
  int wave = t >> 6;                      // 0..7
  int wm = (wave & 3) * 64, wn = (wave >> 2) * 64;
  f32x4 acc[4][4] = {};

  // ---- A staging addresses: pre-swizzled global src, linear LDS dest ----
  const unsigned short* gA[4]; unsigned short* lA[4];
#pragma unroll
  for (int j = 0; j < 4; ++j) {
    int p = t + 512 * j;                  // 0..2047
    int m = p >> 3;
    int kc = (p & 7) ^ (m & 7);
    gA[j] = xb + (size_t)(m0 + m) * D_ + kc * 8;
    lA[j] = Ab + p * 8;
  }

  // ---- B staging: thread owns col (t&127) x chunks {kcp, kcp+4} ----
  int col = t & 127;
  int kcp = t >> 7;                       // 0..3
  bool vok = (n0 + col) < V_;
  const float* wc0 = w + (size_t)(kcp * 8) * V_ + n0 + col;        // chunk kcp
  const float* wc1 = w + (size_t)((kcp + 4) * 8) * V_ + n0 + col;  // chunk kcp+4
  unsigned short* bd0 = &Bb[(col * 8 + (kcp ^ (col & 7))) * 8];
  unsigned short* bd1 = &Bb[(col * 8 + ((kcp + 4) ^ (col & 7))) * 8];
  float ssq = 0.0f;

  int h = l15 & 7;
  for (int kt = 0; kt < D_; kt += BK) {
    // issue A DMA first (latency ticks under the B load/convert below)
#pragma unroll
    for (int j = 0; j < 4; ++j) async_copy16(lA[j], gA[j] + kt);

    // B: 16 stride-V scalar loads (256B/wave-instr), convert, 2x b128 write
    US8 p0 = {}, p1 = {};
    if (vok) {
      const float* a0 = wc0 + (size_t)kt * V_;
      const float* a1 = wc1 + (size_t)kt * V_;
#pragma unroll
      for (int i = 0; i < 8; ++i) {
        float v0 = a0[(size_t)i * V_];
        float v1 = a1[(size_t)i * V_];
        ssq += v0 * v0 + v1 * v1;
        p0.h[i] = f2bf(v0);
        p1.h[i] = f2bf(v1);
      }
    }
    *(US8*)bd0 = p0;
    *(US8*)bd1 = p1;
    __syncthreads();            // drains A-DMA; B writes visible

#pragma unroll
    for (int s = 0; s < 2; ++s) {
      int kx = s * 4 + q;
      bf16x8 af[4], bfr[4];
#pragma unroll
      for (int ri = 0; ri < 4; ++ri) {
        int row_ = wm + ri * 16 + l15;
        af[ri] = *(const bf16x8*)&Ab[(row_ * 8 + (kx ^ h)) * 8];
      }
#pragma unroll
      for (int ci = 0; ci < 4; ++ci) {
        int row_ = wn + ci * 16 + l15;
        bfr[ci] = *(const bf16x8*)&Bb[(row_ * 8 + (kx ^ h)) * 8];
      }
#pragma unroll
      for (int ri = 0; ri < 4; ++ri)
#pragma unroll
        for (int ci = 0; ci < 4; ++ci)
          acc[ri][ci] = __builtin_amdgcn_mfma_f32_16x16x32_bf16(
              af[ri], bfr[ci], acc[ri][ci], 0, 0, 0);
    }
    __syncthreads();            // Ab/Bb safe to overwrite next iter
  }

  // ---- column inv-norms: ssq is block-complete over K ----
  sqred[kcp][col] = ssq;
  __syncthreads();
  if (t < BN) {
    float tot = sqred[0][t] + sqred[1][t] + sqred[2][t] + sqred[3][t];
    iwL[t] = ((n0 + t) < V_) ? 1.0f / fmaxf(sqrtf(tot), 1e-12f) : 0.0f;
  }
  __syncthreads();

  // ---- epilogue: C/D layout col = lane&15 (n side), row = q*4 + reg ----
  float iw[4]; int vcol[4];
#pragma unroll
  for (int ci = 0; ci < 4; ++ci) {
    int nl = wn + ci * 16 + l15;
    vcol[ci] = n0 + nl;
    iw[ci] = iwL[nl];
  }
#pragma unroll
  for (int ri = 0; ri < 4; ++ri) {
#pragma unroll
    for (int reg = 0; reg < 4; ++reg) {
      int ml = wm + ri * 16 + q * 4 + reg;
      int r = m0 + ml;
      int lab = labT[ml];
      float s = 0.0f;
#pragma unroll
      for (int ci = 0; ci < 4; ++ci) {
        float cv = acc[ri][ci][reg] * iw[ci];
        cv = fminf(fmaxf(cv, -1.0f + EPS_), 1.0f - EPS_);
        float logit = cv;
        if (vcol[ci] == lab) {
          logit = cv * COSM - sqrtf(fmaxf(1.0f - cv * cv, 0.0f)) * SINM;
          Lb[r] = logit;               // unique writer across grid
        }
        s += (vcol[ci] < V_) ? __expf(logit) : 0.0f;
      }
      s += __shfl_xor(s, 1, 64);
      s += __shfl_xor(s, 2, 64);
      s += __shfl_xor(s, 4, 64);
      s += __shfl_xor(s, 8, 64);
      if (l15 == 0) atomicAdd(&S[r], s);
    }
  }
}

// ---------------------------------------------------------------------------
// Kernel 3: loss = mean(log(S) - label_logit)
// ---------------------------------------------------------------------------
__global__ void finalk(const float* __restrict__ S, const float* __restrict__ Lb,
                       float* __restrict__ out) {
  __shared__ float red[256];
  int t = threadIdx.x;
  float s = 0.0f;
  for (int i = t; i < B_; i += 256) s += logf(S[i]) - Lb[i];
  red[t] = s;
  __syncthreads();
  for (int o = 128; o > 0; o >>= 1) {
    if (t < o) red[t] += red[t + o];
    __syncthreads();
  }
  if (t == 0) out[0] = red[0] * (1.0f / B_);
}

// ---------------------------------------------------------------------------
extern "C" void kernel_launch(void* const* d_in, const int* in_sizes, int n_in,
                              void* d_out, int out_size, void* d_ws, size_t ws_size,
                              hipStream_t stream) {
  const float* x = (const float*)d_in[0];
  const float* w = (const float*)d_in[1];
  const int* labels = (const int*)d_in[2];
  float* out = (float*)d_out;
  char* ws = (char*)d_ws;
  // ws layout (16B-aligned):
  //   xb : 1024*512 bf16 = 1,048,576 B
  //   S  : 1024 f32, Lb : 1024 f32
  unsigned short* xb = (unsigned short*)ws;
  float* S  = (float*)(ws + 1048576ull);
  float* Lb = (float*)(ws + 1052672ull);

  x_prep<<<256, 256, 0, stream>>>(x, xb, S);
  gemm_fused<<<3136, 512, 0, stream>>>(xb, w, labels, S, Lb);
  finalk<<<1, 256, 0, stream>>>(S, Lb, out);
}

// Round 7
// 457.882 us; speedup vs baseline: 1.5349x; 1.0039x over previous
//
#include <hip/hip_runtime.h>
#include <math.h>

// Problem constants
#define B_    1024
#define D_    512
#define V_    100000
#define NT_   782             // n-tiles of 128 (782*128 = 100096)
#define EPS_  1e-7f
#define COSM  0.9210609940028851f   // cos(0.4)
#define SINM  0.3894183423086505f   // sin(0.4)

typedef __bf16 bf16x8 __attribute__((ext_vector_type(8)));
typedef float  f32x4  __attribute__((ext_vector_type(4)));

struct alignas(16) US8 { unsigned short h[8]; };

// round-to-nearest-even float -> bf16 bits (inputs finite)
__device__ __forceinline__ unsigned short f2bf(float f) {
  union { float f; unsigned u; } a; a.f = f;
  unsigned u = a.u;
  u += 0x7FFFu + ((u >> 16) & 1u);
  return (unsigned short)(u >> 16);
}

__device__ __forceinline__ void async_copy16(void* lds, const void* g) {
  __builtin_amdgcn_global_load_lds(
      (const __attribute__((address_space(1))) void*)g,
      (__attribute__((address_space(3))) void*)lds, 16, 0, 0);
}

// ---------------------------------------------------------------------------
// Kernel 1: L2-normalize rows of x -> bf16; zero S.
// grid 256 x block 256 (4 waves = 4 rows per block)
// ---------------------------------------------------------------------------
__global__ void x_prep(const float* __restrict__ x,
                       unsigned short* __restrict__ xb,
                       float* __restrict__ S) {
  int t = threadIdx.x;
  int lane = t & 63, wave = t >> 6;
  int row = blockIdx.x * 4 + wave;
  const float* xr = x + (size_t)row * D_;
  f32x4 a = *(const f32x4*)(xr + lane * 8);
  f32x4 b = *(const f32x4*)(xr + lane * 8 + 4);
  float ss = a[0]*a[0] + a[1]*a[1] + a[2]*a[2] + a[3]*a[3]
           + b[0]*b[0] + b[1]*b[1] + b[2]*b[2] + b[3]*b[3];
#pragma unroll
  for (int off = 32; off > 0; off >>= 1) ss += __shfl_xor(ss, off, 64);
  float inv = 1.0f / fmaxf(sqrtf(ss), 1e-12f);
  US8 pk;
#pragma unroll
  for (int j = 0; j < 4; ++j) pk.h[j]     = f2bf(a[j] * inv);
#pragma unroll
  for (int j = 0; j < 4; ++j) pk.h[4 + j] = f2bf(b[j] * inv);
  *(US8*)(xb + (size_t)row * D_ + lane * 8) = pk;
  if (lane == 0) S[row] = 0.0f;
}

// ---------------------------------------------------------------------------
// Kernel 2 (v7): v6 (BM=256 x BN=128, 512 thr / 8 waves, inline-B,
// 2 blocks/CU) + EAGER-CONVERT B REGISTER PREFETCH.
// v6's stall: per K-iter the 16 stride-V B-loads' latency (~400-900 cy)
// sat serially before the convert+sync. v7 issues tile t+1's loads right
// after the staging sync and converts them immediately (f2bf+ssq) into two
// packed US8 — only 4 VGPRs live across the MFMA block (R5's raw-f32
// prefetch needed 16 and spilled). Loads+converts are independent of the
// MFMA stream -> scheduler hides them under the MFMA phase; staging at
// iter t+1 collapses to 2x ds_write_b128. ds_write map [col][chunk^(col&7)]
// measured conflict-free (R5/R6: SQ_LDS_BANK_CONFLICT = 0).
// Column ssq block-complete over K -> LDS reduce -> iwL. Fused ArcFace
// epilogue. __launch_bounds__(512,4). grid 3136 x block 512.
// ---------------------------------------------------------------------------
#define BM 256
#define BN 128
#define BK 64

__global__ __launch_bounds__(512, 4) void gemm_fused(
    const unsigned short* __restrict__ xb,
    const float* __restrict__ w,
    const int* __restrict__ labels,
    float* __restrict__ S, float* __restrict__ Lb) {
  int bid = blockIdx.x;
  int xcd = bid & 7;
  int slot = bid >> 3;          // 0..391
  int tm = slot & 3;
  int tn = xcd * 98 + (slot >> 2);
  if (tn >= NT_) return;
  int m0 = tm * BM, n0 = tn * BN;

  // LDS slot p (16B chunks) holds (m = p>>3, kc = (p&7) ^ (m&7))
  __shared__ unsigned short Ab[BM * BK];  // 32 KB
  __shared__ unsigned short Bb[BN * BK];  // 16 KB
  __shared__ float sqred[4][BN];          // 2 KB
  __shared__ float iwL[BN];               // 0.5 KB
  __shared__ int labT[BM];                // 1 KB
  int t = threadIdx.x;
  if (t < BM) labT[t] = labels[m0 + t];
  int lane = t & 63;
  int q = lane >> 4, l15 = lane & 15;
  int wave = t >> 6;                      // 0..7
  int wm = (wave & 3) * 64, wn = (wave >> 2) * 64;
  f32x4 acc[4][4] = {};

  // ---- A staging addresses: pre-swizzled global src, linear LDS dest ----
  const unsigned short* gA[4]; unsigned short* lA[4];
#pragma unroll
  for (int j = 0; j < 4; ++j) {
    int p = t + 512 * j;                  // 0..2047
    int m = p >> 3;
    int kc = (p & 7) ^ (m & 7);
    gA[j] = xb + (size_t)(m0 + m) * D_ + kc * 8;
    lA[j] = Ab + p * 8;
  }

  // ---- B staging: thread owns col (t&127) x chunks {kcp, kcp+4} ----
  int col = t & 127;
  int kcp = t >> 7;                       // 0..3
  bool vok = (n0 + col) < V_;
  const float* wc0 = w + (size_t)(kcp * 8) * V_ + n0 + col;        // chunk kcp
  const float* wc1 = w + (size_t)((kcp + 4) * 8) * V_ + n0 + col;  // chunk kcp+4
  unsigned short* bd0 = &Bb[(col * 8 + (kcp ^ (col & 7))) * 8];
  unsigned short* bd1 = &Bb[(col * 8 + ((kcp + 4) ^ (col & 7))) * 8];
  float ssq = 0.0f;

  // ---- prologue: load + eager-convert B tile 0 into packed regs ----
  US8 pb0 = {}, pb1 = {};
  if (vok) {
#pragma unroll
    for (int i = 0; i < 8; ++i) {
      float v0 = wc0[(size_t)i * V_];
      float v1 = wc1[(size_t)i * V_];
      ssq += v0 * v0 + v1 * v1;
      pb0.h[i] = f2bf(v0);
      pb1.h[i] = f2bf(v1);
    }
  }

  int h = l15 & 7;
  for (int kt = 0; kt < D_; kt += BK) {
    // issue A DMA (async); commit pre-converted B chunks to LDS
#pragma unroll
    for (int j = 0; j < 4; ++j) async_copy16(lA[j], gA[j] + kt);
    *(US8*)bd0 = pb0;
    *(US8*)bd1 = pb1;
    __syncthreads();            // drains A-DMA; B writes visible

    // prefetch + eager-convert NEXT tile's B (hides under MFMA below)
    if (vok && (kt + BK) < D_) {
      const float* a0 = wc0 + (size_t)(kt + BK) * V_;
      const float* a1 = wc1 + (size_t)(kt + BK) * V_;
#pragma unroll
      for (int i = 0; i < 8; ++i) {
        float v0 = a0[(size_t)i * V_];
        float v1 = a1[(size_t)i * V_];
        ssq += v0 * v0 + v1 * v1;
        pb0.h[i] = f2bf(v0);
        pb1.h[i] = f2bf(v1);
      }
    }

#pragma unroll
    for (int s = 0; s < 2; ++s) {
      int kx = s * 4 + q;
      bf16x8 af[4], bfr[4];
#pragma unroll
      for (int ri = 0; ri < 4; ++ri) {
        int row_ = wm + ri * 16 + l15;
        af[ri] = *(const bf16x8*)&Ab[(row_ * 8 + (kx ^ h)) * 8];
      }
#pragma unroll
      for (int ci = 0; ci < 4; ++ci) {
        int row_ = wn + ci * 16 + l15;
        bfr[ci] = *(const bf16x8*)&Bb[(row_ * 8 + (kx ^ h)) * 8];
      }
#pragma unroll
      for (int ri = 0; ri < 4; ++ri)
#pragma unroll
        for (int ci = 0; ci < 4; ++ci)
          acc[ri][ci] = __builtin_amdgcn_mfma_f32_16x16x32_bf16(
              af[ri], bfr[ci], acc[ri][ci], 0, 0, 0);
    }
    __syncthreads();            // Ab/Bb safe to overwrite next iter
  }

  // ---- column inv-norms: ssq is block-complete over K ----
  sqred[kcp][col] = ssq;
  __syncthreads();
  if (t < BN) {
    float tot = sqred[0][t] + sqred[1][t] + sqred[2][t] + sqred[3][t];
    iwL[t] = ((n0 + t) < V_) ? 1.0f / fmaxf(sqrtf(tot), 1e-12f) : 0.0f;
  }
  __syncthreads();

  // ---- epilogue: C/D layout col = lane&15 (n side), row = q*4 + reg ----
  float iw[4]; int vcol[4];
#pragma unroll
  for (int ci = 0; ci < 4; ++ci) {
    int nl = wn + ci * 16 + l15;
    vcol[ci] = n0 + nl;
    iw[ci] = iwL[nl];
  }
#pragma unroll
  for (int ri = 0; ri < 4; ++ri) {
#pragma unroll
    for (int reg = 0; reg < 4; ++reg) {
      int ml = wm + ri * 16 + q * 4 + reg;
      int r = m0 + ml;
      int lab = labT[ml];
      float s = 0.0f;
#pragma unroll
      for (int ci = 0; ci < 4; ++ci) {
        float cv = acc[ri][ci][reg] * iw[ci];
        cv = fminf(fmaxf(cv, -1.0f + EPS_), 1.0f - EPS_);
        float logit = cv;
        if (vcol[ci] == lab) {
          logit = cv * COSM - sqrtf(fmaxf(1.0f - cv * cv, 0.0f)) * SINM;
          Lb[r] = logit;               // unique writer across grid
        }
        s += (vcol[ci] < V_) ? __expf(logit) : 0.0f;
      }
      s += __shfl_xor(s, 1, 64);
      s += __shfl_xor(s, 2, 64);
      s += __shfl_xor(s, 4, 64);
      s += __shfl_xor(s, 8, 64);
      if (l15 == 0) atomicAdd(&S[r], s);
    }
  }
}

// ---------------------------------------------------------------------------
// Kernel 3: loss = mean(log(S) - label_logit)
// ---------------------------------------------------------------------------
__global__ void finalk(const float* __restrict__ S, const float* __restrict__ Lb,
                       float* __restrict__ out) {
  __shared__ float red[256];
  int t = threadIdx.x;
  float s = 0.0f;
  for (int i = t; i < B_; i += 256) s += logf(S[i]) - Lb[i];
  red[t] = s;
  __syncthreads();
  for (int o = 128; o > 0; o >>= 1) {
    if (t < o) red[t] += red[t + o];
    __syncthreads();
  }
  if (t == 0) out[0] = red[0] * (1.0f / B_);
}

// ---------------------------------------------------------------------------
extern "C" void kernel_launch(void* const* d_in, const int* in_sizes, int n_in,
                              void* d_out, int out_size, void* d_ws, size_t ws_size,
                              hipStream_t stream) {
  const float* x = (const float*)d_in[0];
  const float* w = (const float*)d_in[1];
  const int* labels = (const int*)d_in[2];
  float* out = (float*)d_out;
  char* ws = (char*)d_ws;
  // ws layout (16B-aligned):
  //   xb : 1024*512 bf16 = 1,048,576 B
  //   S  : 1024 f32, Lb : 1024 f32
  unsigned short* xb = (unsigned short*)ws;
  float* S  = (float*)(ws + 1048576ull);
  float* Lb = (float*)(ws + 1052672ull);

  x_prep<<<256, 256, 0, stream>>>(x, xb, S);
  gemm_fused<<<3136, 512, 0, stream>>>(xb, w, labels, S, Lb);
  finalk<<<1, 256, 0, stream>>>(S, Lb, out);
}